// Round 10
// baseline (24.421 us; speedup 1.0000x reference)
//
#include <hip/hip_runtime.h>

// Problem constants (from reference)
#define NRB 512
#define NTK 1024
#define DD  64
#define GHH 128

// Dead dataflow: tgt = edge_index[1]+512 in [512,1536) but robot_msgs =
// agg[:512] -> all-zero => edge MLP + segment_sum dead. lrelu(x) =
// 0.55x + 0.45|x| factors score into a[n] + c[m] + sum_h wb[h]*|HR+HTB|.
//
// R2: grid.sync ~60us -> kernel boundaries. R3: 256 VGPR -> latency-bound.
// R4: uncoalesced row reads -> transpose. R5: reg-array staging spills.
// R6-R8: score rewrites ~neutral. R9: all-b128 prep -3.2us => LDS issue
// count was real. R10: robot MLP is block-local -> fold it into the score
// kernel (phase A computes hr/av/wb straight into LDS); kernel 1 shrinks
// to task-only. Deletes HR/av/wbv global round-trips + half of prep.

// Workspace layout (floats):
//   HTBt4 [32][1024][4]  @ 0        (h-interleaved transpose, incl bm1)
//   c     [1024]         @ 131072   (incl bm2)

// ---------------------------------------------------------------------------
// Kernel 1: task prep. 128 blocks x 256 threads; block b -> tasks 8b..8b+7.
// HTBt4[h4][m] = (x_task@Wm1[:,128:].T + bm1) packed 4-h per f4; cv[m].
// ---------------------------------------------------------------------------
__global__ __launch_bounds__(256) void task_prep_kernel(
    const float* __restrict__ xt,
    const float* __restrict__ Wm1, const float* __restrict__ bm1,
    const float* __restrict__ Wm2, const float* __restrict__ bm2,
    float* __restrict__ HTBt4, float* __restrict__ cv)
{
    const int t = threadIdx.x;   // 0..255
    const int b = blockIdx.x;    // 0..127
    const int i = t & 127;       // output neuron
    const int g = t >> 7;        // row-group 0/1

    __shared__ float lds_w[128 * 132];   // row-major weights, stride 132
    __shared__ float xs[8 * 64];
    __shared__ float sT[8 * 132];
    __shared__ float sR[8 * 132];

    float4* Lw = reinterpret_cast<float4*>(lds_w);

    const int t0 = b * 8;
    xs[t]       = xt[t0 * DD + t];
    xs[256 + t] = xt[t0 * DD + 256 + t];

    // stage Wt = Wm1[:,128:192]: 2048 f4
    {
        const float4* W = reinterpret_cast<const float4*>(Wm1);
        #pragma unroll
        for (int j = 0; j < 8; ++j) {
            const int e = t + 256 * j;
            const int row = e >> 4, c4 = e & 15;
            Lw[row * 33 + c4] = W[row * 48 + 32 + c4];
        }
    }
    __syncthreads();

    // rows 4g..4g+3: htb = x_task @ Wt^T + bm1
    {
        const float bb  = bm1[i];
        const float wm2 = Wm2[i];
        float a0 = bb, a1 = bb, a2 = bb, a3 = bb;
        const float4* w4 = Lw + i * 33;
        const float4* x0 = reinterpret_cast<const float4*>(xs + (4*g)*64);
        const float4* x1 = reinterpret_cast<const float4*>(xs + (4*g+1)*64);
        const float4* x2 = reinterpret_cast<const float4*>(xs + (4*g+2)*64);
        const float4* x3 = reinterpret_cast<const float4*>(xs + (4*g+3)*64);
        #pragma unroll
        for (int k = 0; k < 16; ++k) {
            const float4 w = w4[k];
            const float4 p0 = x0[k], p1 = x1[k], p2 = x2[k], p3 = x3[k];
            a0 = fmaf(w.x, p0.x, a0); a1 = fmaf(w.x, p1.x, a1);
            a2 = fmaf(w.x, p2.x, a2); a3 = fmaf(w.x, p3.x, a3);
            a0 = fmaf(w.y, p0.y, a0); a1 = fmaf(w.y, p1.y, a1);
            a2 = fmaf(w.y, p2.y, a2); a3 = fmaf(w.y, p3.y, a3);
            a0 = fmaf(w.z, p0.z, a0); a1 = fmaf(w.z, p1.z, a1);
            a2 = fmaf(w.z, p2.z, a2); a3 = fmaf(w.z, p3.z, a3);
            a0 = fmaf(w.w, p0.w, a0); a1 = fmaf(w.w, p1.w, a1);
            a2 = fmaf(w.w, p2.w, a2); a3 = fmaf(w.w, p3.w, a3);
        }
        sT[(4*g)*132 + i]   = a0;  sR[(4*g)*132 + i]   = wm2 * a0;
        sT[(4*g+1)*132 + i] = a1;  sR[(4*g+1)*132 + i] = wm2 * a1;
        sT[(4*g+2)*132 + i] = a2;  sR[(4*g+2)*132 + i] = wm2 * a2;
        sT[(4*g+3)*132 + i] = a3;  sR[(4*g+3)*132 + i] = wm2 * a3;
    }
    __syncthreads();

    // interleaved transposed write: HTBt4[h4][t0+tk] = htb[tk][4h4..4h4+3]
    {
        const int h4 = t >> 3, tk = t & 7;
        float4 v;
        v.x = sT[tk*132 + 4*h4 + 0];
        v.y = sT[tk*132 + 4*h4 + 1];
        v.z = sT[tk*132 + 4*h4 + 2];
        v.w = sT[tk*132 + 4*h4 + 3];
        reinterpret_cast<float4*>(HTBt4)[h4 * NTK + t0 + tk] = v;
    }

    // c[m] = 0.55 * sum_i sR[m][i] + bm2;  half-wave per task
    {
        const int row = t >> 5, c = t & 31;
        float s = sR[row*132 + c]      + sR[row*132 + c + 32]
                + sR[row*132 + c + 64] + sR[row*132 + c + 96];
        #pragma unroll
        for (int off = 16; off >= 1; off >>= 1)
            s += __shfl_xor(s, off, 32);
        if (c == 0) cv[t0 + row] = 0.55f * s + bm2[0];
    }
}

// ---------------------------------------------------------------------------
// Kernel 2: robot MLP + score + softmax. 256 blocks x 1024 threads.
// Block b owns robot rows n0=2b,2b+1 and ALL 1024 m (thread tid = m).
// Phase A: stage W1/W2/W3 to LDS (coalesced f4, all 1024 threads); 256
// threads compute h1 -> h -> hr for the 2 rows; hr/av/wb stay in LDS.
// Phase B: 32 iters of {1 coalesced dwordx4 HTBt4 + 3 LDS f4 broadcasts +
// 16 VALU}; block softmax; coalesced store.
// ---------------------------------------------------------------------------
__global__ __launch_bounds__(1024) void robot_score_softmax_kernel(
    const float* __restrict__ xr,
    const float* __restrict__ Wv1, const float* __restrict__ bv1,
    const float* __restrict__ Wv2, const float* __restrict__ bv2,
    const float* __restrict__ Wm1, const float* __restrict__ Wm2,
    const float* __restrict__ HTBt4, const float* __restrict__ cv,
    float* __restrict__ out)
{
    const int b   = blockIdx.x;     // 0..255
    const int tid = threadIdx.x;    // 0..1023 == m
    const int n0  = b * 2;

    __shared__ float lds_w[128 * 132];   // 67.6 KB weights
    __shared__ float xs[2 * 64];
    __shared__ float sA[2 * 132];
    __shared__ float sB[2 * 132];
    __shared__ float sR[2 * 132];
    __shared__ float s_hr[2 * 128];
    __shared__ float s_wb[128];
    __shared__ float s_av[2];

    float4* Lw = reinterpret_cast<float4*>(lds_w);

    // load cv early (hide under phase A)
    const float cm = cv[tid];

    // ---------------- Phase A: robot MLP for rows n0, n0+1 ----------------
    if (tid < 128) xs[tid] = xr[n0 * DD + tid];

    // stage W1 = Wv1[:,128:192]: 2048 f4
    {
        const float4* W = reinterpret_cast<const float4*>(Wv1);
        #pragma unroll
        for (int j = 0; j < 2; ++j) {
            const int e = tid + 1024 * j;        // 0..2047
            const int row = e >> 4, c4 = e & 15;
            Lw[row * 33 + c4] = W[row * 48 + 32 + c4];
        }
    }
    __syncthreads();

    // h1 = lrelu(x @ W1^T + bv1)   (256 compute threads)
    if (tid < 256) {
        const int i = tid & 127, r = tid >> 7;
        float acc = bv1[i];
        const float4* w4 = Lw + i * 33;
        const float4* x4 = reinterpret_cast<const float4*>(xs + r * 64);
        #pragma unroll
        for (int k = 0; k < 16; ++k) {
            const float4 w = w4[k];
            const float4 p = x4[k];
            acc = fmaf(w.x, p.x, acc);
            acc = fmaf(w.y, p.y, acc);
            acc = fmaf(w.z, p.z, acc);
            acc = fmaf(w.w, p.w, acc);
        }
        sA[r*132 + i] = (acc >= 0.f) ? acc : 0.1f * acc;
    }
    __syncthreads();

    // stage W2 = Wv2: 4096 f4
    {
        const float4* W = reinterpret_cast<const float4*>(Wv2);
        #pragma unroll
        for (int j = 0; j < 4; ++j) {
            const int e = tid + 1024 * j;        // 0..4095
            const int row = e >> 5, c4 = e & 31;
            Lw[row * 33 + c4] = W[row * 32 + c4];
        }
    }
    __syncthreads();

    // h = h1 @ W2^T + bv2
    if (tid < 256) {
        const int i = tid & 127, r = tid >> 7;
        float acc = bv2[i];
        const float4* w4 = Lw + i * 33;
        const float4* h4 = reinterpret_cast<const float4*>(sA + r * 132);
        #pragma unroll 8
        for (int k = 0; k < 32; ++k) {
            const float4 w = w4[k];
            const float4 p = h4[k];
            acc = fmaf(w.x, p.x, acc);
            acc = fmaf(w.y, p.y, acc);
            acc = fmaf(w.z, p.z, acc);
            acc = fmaf(w.w, p.w, acc);
        }
        sB[r*132 + i] = acc;
    }
    __syncthreads();

    // stage W3 = Wm1[:, :128]: 4096 f4; also wb = 0.45*Wm2
    {
        const float4* W = reinterpret_cast<const float4*>(Wm1);
        #pragma unroll
        for (int j = 0; j < 4; ++j) {
            const int e = tid + 1024 * j;
            const int row = e >> 5, c4 = e & 31;
            Lw[row * 33 + c4] = W[row * 48 + c4];
        }
        if (tid < 128) s_wb[tid] = 0.45f * Wm2[tid];
    }
    __syncthreads();

    // hr = h @ W3^T; products for a[n]
    if (tid < 256) {
        const int i = tid & 127, r = tid >> 7;
        float acc = 0.f;
        const float4* w4 = Lw + i * 33;
        const float4* h4 = reinterpret_cast<const float4*>(sB + r * 132);
        #pragma unroll 8
        for (int k = 0; k < 32; ++k) {
            const float4 w = w4[k];
            const float4 p = h4[k];
            acc = fmaf(w.x, p.x, acc);
            acc = fmaf(w.y, p.y, acc);
            acc = fmaf(w.z, p.z, acc);
            acc = fmaf(w.w, p.w, acc);
        }
        s_hr[r*128 + i] = acc;
        sR[r*132 + i]   = Wm2[i] * acc;
    }
    __syncthreads();

    // a[n] = 0.55 * sum_i sR[n][i]   (waves 0-1, one per row)
    if (tid < 128) {
        const int w = tid >> 6, l = tid & 63;
        float s = sR[w*132 + l] + sR[w*132 + l + 64];
        #pragma unroll
        for (int off = 32; off >= 1; off >>= 1)
            s += __shfl_xor(s, off, 64);
        if (l == 0) s_av[w] = 0.55f * s;
    }
    __syncthreads();

    // ---------------- Phase B: score + softmax ----------------
    const float4* tb  = reinterpret_cast<const float4*>(HTBt4) + tid;
    const float4* hrA = reinterpret_cast<const float4*>(s_hr);
    const float4* hrB = reinterpret_cast<const float4*>(s_hr + 128);
    const float4* wb4 = reinterpret_cast<const float4*>(s_wb);

    float acc0 = 0.f, acc1 = 0.f;

    #pragma unroll 4
    for (int h4 = 0; h4 < 32; ++h4) {
        const float4 v  = tb[h4 << 10];     // coalesced dwordx4
        const float4 w  = wb4[h4];          // LDS broadcast
        const float4 r0 = hrA[h4];
        const float4 r1 = hrB[h4];
        acc0 = fmaf(w.x, fabsf(r0.x + v.x), acc0);
        acc1 = fmaf(w.x, fabsf(r1.x + v.x), acc1);
        acc0 = fmaf(w.y, fabsf(r0.y + v.y), acc0);
        acc1 = fmaf(w.y, fabsf(r1.y + v.y), acc1);
        acc0 = fmaf(w.z, fabsf(r0.z + v.z), acc0);
        acc1 = fmaf(w.z, fabsf(r1.z + v.z), acc1);
        acc0 = fmaf(w.w, fabsf(r0.w + v.w), acc0);
        acc1 = fmaf(w.w, fabsf(r1.w + v.w), acc1);
    }

    float sc[2];
    sc[0] = acc0 + s_av[0] + cm;
    sc[1] = acc1 + s_av[1] + cm;

    // ---- block-local softmax over the 1024 columns, both rows ----
    __shared__ float rmax[2][16], rsum[2][16];
    const int wid = tid >> 6, lane = tid & 63;

    #pragma unroll
    for (int n = 0; n < 2; ++n) {
        float mx = sc[n];
        #pragma unroll
        for (int off = 32; off >= 1; off >>= 1)
            mx = fmaxf(mx, __shfl_xor(mx, off, 64));
        if (lane == 0) rmax[n][wid] = mx;
    }
    __syncthreads();

    float ex[2];
    #pragma unroll
    for (int n = 0; n < 2; ++n) {
        float mx = rmax[n][0];
        #pragma unroll
        for (int k = 1; k < 16; ++k) mx = fmaxf(mx, rmax[n][k]);
        float e = expf(sc[n] - mx);
        ex[n] = e;
        float s = e;
        #pragma unroll
        for (int off = 32; off >= 1; off >>= 1) s += __shfl_xor(s, off, 64);
        if (lane == 0) rsum[n][wid] = s;
    }
    __syncthreads();

    #pragma unroll
    for (int n = 0; n < 2; ++n) {
        float s = rsum[n][0];
        #pragma unroll
        for (int k = 1; k < 16; ++k) s += rsum[n][k];
        out[(n0 + n) * NTK + tid] = ex[n] * (1.0f / s);
    }
}

extern "C" void kernel_launch(void* const* d_in, const int* in_sizes, int n_in,
                              void* d_out, int out_size, void* d_ws, size_t ws_size,
                              hipStream_t stream)
{
    const float* xr  = (const float*)d_in[0];
    const float* xt  = (const float*)d_in[1];
    // d_in[2]=edge_index, [3]=edge_attr, [4..7]=We1,be1,We2,be2 : provably dead
    const float* Wv1 = (const float*)d_in[8];
    const float* bv1 = (const float*)d_in[9];
    const float* Wv2 = (const float*)d_in[10];
    const float* bv2 = (const float*)d_in[11];
    const float* Wm1 = (const float*)d_in[12];
    const float* bm1 = (const float*)d_in[13];
    const float* Wm2 = (const float*)d_in[14];
    const float* bm2 = (const float*)d_in[15];

    float* ws    = (float*)d_ws;
    float* HTBt4 = ws;
    float* cv    = ws + 131072;
    float* out   = (float*)d_out;

    hipLaunchKernelGGL(task_prep_kernel, dim3(128), dim3(256), 0, stream,
                       xt, Wm1, bm1, Wm2, bm2, HTBt4, cv);
    hipLaunchKernelGGL(robot_score_softmax_kernel, dim3(256), dim3(1024), 0, stream,
                       xr, Wv1, bv1, Wv2, bv2, Wm1, Wm2, HTBt4, cv, out);
}